// Round 13
// baseline (210.813 us; speedup 1.0000x reference)
//
#include <hip/hip_runtime.h>

#define B_ 8
#define N_ 1025
#define D_ 768
#define H_ 12
#define NP_ 1024
#define ROWS_ (B_*N_)        /* 8200 */
#define ROWS_PAD_ 8320       /* 65*128 */
#define QKVC_ 2304
#define SCALE_ 0.03608439182435161f  /* 768^-0.5 */
#define EPS_ 1e-5f

typedef float f32x4 __attribute__((ext_vector_type(4)));
typedef short s16x8 __attribute__((ext_vector_type(8)));

// async global->LDS, 16B per lane; lds dest must be wave-uniform base + lane*16
#define GLD16(g, l) __builtin_amdgcn_global_load_lds( \
    (const __attribute__((address_space(1))) unsigned int*)(g), \
    (__attribute__((address_space(3))) unsigned int*)(l), 16, 0, 0)

__device__ __forceinline__ float blo(unsigned int u){
  union { unsigned int i; float f; } v; v.i = u << 16; return v.f;
}
__device__ __forceinline__ float bhi(unsigned int u){
  union { unsigned int i; float f; } v; v.i = u & 0xffff0000u; return v.f;
}
__device__ __forceinline__ float bf2f(unsigned short u){
  union { unsigned int i; float f; } v; v.i = ((unsigned int)u) << 16; return v.f;
}
__device__ __forceinline__ unsigned short f2bf(float f){
  union { unsigned int i; float f; } v; v.f = f;
  unsigned int b = v.i;
  b = b + 0x7fffu + ((b >> 16) & 1u);
  return (unsigned short)(b >> 16);
}
// pack two f32 -> two bf16 (round-half-up, bit-identical to f2bf pairs), 3 VALU.
// NOTE (r4/r7/r8, isolated by r8-vs-r9): do NOT replace with inline-asm
// v_cvt_pk_bf16_f32 when inputs come from __expf/v_exp_f32 -- the TRANS-op
// latency hazard is not fenced ahead of INLINEASM consumers (reads stale regs,
// absmax ~1.4e-2). pkbf2 uses compiler-visible ops -> hazard handled.
// NOTE (r10): removing the post-exp attn barrier (even with lgkmcnt+sched_barrier
// fence) REGRESSES: VGPR 76->92, FETCH +33%, dur +5.5us. Keep 3 barriers/jt.
// NOTE (r11): GEMM BK=32 retile regresses (+10us E2E): halving BK doubles the
// barrier/vmcnt step count, which IS the binding cost (m233) -- keep BK=64.
// NOTE (r12): 512-thr/8-wave GEMM at SAME geometry = -7us (occupancy lever).
__device__ __forceinline__ unsigned int pkbf2(float a, float b){
  union { float f; unsigned int i; } ua, ub;
  ua.f = a; ub.f = b;
  return __builtin_amdgcn_perm(ub.i + 0x8000u, ua.i + 0x8000u, 0x07060302u);
}

// ---------------- prep: fused weight transposes + layernorm ----------------
// blocks 0..2303: transpose (768 x N) fp32 -> (N x 768) bf16 (two weights)
// blocks 2304..10503: layernorm row (id-2304), 192 active lanes, float4 loads
__global__ __launch_bounds__(256) void prep_fused(
    const float* __restrict__ w1, unsigned short* __restrict__ d1,
    const float* __restrict__ w2, unsigned short* __restrict__ d2,
    const float* __restrict__ x, const float* __restrict__ lw,
    const float* __restrict__ lb, unsigned short* __restrict__ xn) {
  int id = blockIdx.x;
  int t = threadIdx.x;
  if (id < 2304) {
    __shared__ unsigned short tile[32][33];
    int bx = id % 96;
    int kb = (id / 96) * 32;
    const float* src; unsigned short* dst; int N, nb;
    if (bx < 72) { src = w1; dst = d1; N = QKVC_; nb = bx * 32; }
    else         { src = w2; dst = d2; N = D_;    nb = (bx - 72) * 32; }
    int tx = t & 31, ty = t >> 5;  // 32 x 8
    #pragma unroll
    for (int i = 0; i < 4; i++) {
      int r = ty + i * 8;
      tile[r][tx] = f2bf(src[(size_t)(kb + r) * N + nb + tx]);
    }
    __syncthreads();
    #pragma unroll
    for (int i = 0; i < 4; i++) {
      int r = ty + i * 8;
      dst[(size_t)(nb + r) * D_ + kb + tx] = tile[tx][r];
    }
  } else {
    int row = id - 2304;
    __shared__ float r6[6];
    float4 v; float s = 0.f, q = 0.f;
    if (t < 192) {
      v = ((const float4*)(x + (size_t)row * D_))[t];
      s = v.x + v.y + v.z + v.w;
      q = v.x * v.x + v.y * v.y + v.z * v.z + v.w * v.w;
      #pragma unroll
      for (int off = 32; off > 0; off >>= 1) {
        s += __shfl_xor(s, off, 64);
        q += __shfl_xor(q, off, 64);
      }
      if ((t & 63) == 0) { r6[t >> 6] = s; r6[3 + (t >> 6)] = q; }
    }
    __syncthreads();
    if (t < 192) {
      s = r6[0] + r6[1] + r6[2];
      q = r6[3] + r6[4] + r6[5];
      float mean = s * (1.0f / 768.0f);
      float var = q * (1.0f / 768.0f) - mean * mean;
      var = var < 0.f ? 0.f : var;
      float rstd = rsqrtf(var + EPS_);
      float4 wv4 = ((const float4*)lw)[t];
      float4 bv4 = ((const float4*)lb)[t];
      float o0 = (v.x - mean) * rstd * wv4.x + bv4.x;
      float o1 = (v.y - mean) * rstd * wv4.y + bv4.y;
      float o2 = (v.z - mean) * rstd * wv4.z + bv4.z;
      float o3 = (v.w - mean) * rstd * wv4.w + bv4.w;
      uint2 pk = {pkbf2(o0, o1), pkbf2(o2, o3)};
      *(uint2*)(xn + (size_t)row * D_ + t * 4) = pk;
    }
  }
}

// ---------------- GEMM: C[M][N] = A[M][K] * Bt[N][K]^T (+bias)
// r12 (kept): 128x128 tile / BK=64 / 64KB dbuf LDS / 2-phase pipeline /
// T2 swizzle / T1 XCD swizzle, 512 thr / 8 waves (wave tile 64x32) ->
// 16 waves/CU hides the per-K-step vmcnt(0)+barrier stall.
template <bool OF32>
__global__ __launch_bounds__(512) void gemm_bt(
    const unsigned short* __restrict__ A, const unsigned short* __restrict__ Bt,
    void* __restrict__ Cv, const float* __restrict__ bias,
    int Mvalid, int Nn, int Kk) {
  __shared__ short sh[32768];  // 64KB: As[2][8192] | Bs[2][8192]; reused as C-stage
  int t = threadIdx.x;
  int lane = t & 63, w = t >> 6;
  int m16 = lane & 15, quad = lane >> 4;

  // bijective XCD swizzle (m204)
  int nwg = gridDim.x;
  int nbx = Nn >> 7;
  int id = blockIdx.x;
  int qq = nwg >> 3, rr = nwg & 7;
  int xcd = id & 7, off = id >> 3;
  int wg = (xcd < rr ? xcd * (qq + 1) : rr * (qq + 1) + (xcd - rr) * qq) + off;
  int bx = wg % nbx, by = wg / nbx;
  int bm = by * 128, bn = bx * 128;

  int wm = (w & 1) * 64, wn = (w >> 1) * 32;  // 2M x 4N waves, wave tile 64x32

  f32x4 acc[4][2];
  #pragma unroll
  for (int i = 0; i < 4; i++)
    #pragma unroll
    for (int j = 0; j < 2; j++) acc[i][j] = (f32x4){0.f, 0.f, 0.f, 0.f};

  const unsigned short* aP[2];
  const unsigned short* bP[2];
  #pragma unroll
  for (int c = 0; c < 2; c++) {
    int g = t + c * 512;
    int row = g >> 3, slot = g & 7;
    aP[c] = A  + (size_t)(bm + row) * Kk + ((slot ^ (row & 7)) * 8);
    bP[c] = Bt + (size_t)(bn + row) * Kk + ((slot ^ (row & 7)) * 8);
  }

  int KS = Kk >> 6;  // 12
  int cur = 0;
  #pragma unroll
  for (int c = 0; c < 2; c++) GLD16(aP[c], sh + (t + c * 512) * 8);
  #pragma unroll
  for (int c = 0; c < 2; c++) GLD16(bP[c], sh + 16384 + (t + c * 512) * 8);

  for (int kt = 0; kt < KS; kt++) {
    asm volatile("s_waitcnt vmcnt(0)" ::: "memory");
    __builtin_amdgcn_s_barrier();
    if (kt + 1 < KS) {
      int nb2 = (cur ^ 1) * 8192;
      int ko = (kt + 1) * 64;
      #pragma unroll
      for (int c = 0; c < 2; c++) GLD16(aP[c] + ko, sh + nb2 + (t + c * 512) * 8);
      #pragma unroll
      for (int c = 0; c < 2; c++) GLD16(bP[c] + ko, sh + 16384 + nb2 + (t + c * 512) * 8);
    }
    const short* sa = sh + cur * 8192;
    const short* sb = sh + 16384 + cur * 8192;
    #pragma unroll
    for (int ks = 0; ks < 2; ks++) {
      int so = ((ks * 4 + quad) ^ (m16 & 7)) * 8;
      s16x8 af[4], bfr[2];
      #pragma unroll
      for (int i = 0; i < 4; i++)
        af[i] = *(const s16x8*)(sa + (wm + i * 16 + m16) * 64 + so);
      #pragma unroll
      for (int j = 0; j < 2; j++)
        bfr[j] = *(const s16x8*)(sb + (wn + j * 16 + m16) * 64 + so);
      __builtin_amdgcn_s_setprio(1);
      #pragma unroll
      for (int i = 0; i < 4; i++)
        #pragma unroll
        for (int j = 0; j < 2; j++)
          acc[i][j] = __builtin_amdgcn_mfma_f32_16x16x32_bf16(af[i], bfr[j], acc[i][j], 0, 0, 0);
      __builtin_amdgcn_s_setprio(0);
    }
    cur ^= 1;
  }
  __syncthreads();  // all LDS reads done; no loads in flight (last iter staged none)

  if (!OF32) {
    unsigned short* C = (unsigned short*)Cv;
    #pragma unroll
    for (int j = 0; j < 2; j++) {
      int col = wn + j * 16 + m16;
      #pragma unroll
      for (int i = 0; i < 4; i++)
        #pragma unroll
        for (int r = 0; r < 4; r++)
          sh[(wm + i * 16 + quad * 4 + r) * 128 + col] = (short)f2bf(acc[i][j][r]);
    }
    __syncthreads();
    #pragma unroll
    for (int c = 0; c < 4; c++) {
      int idx = c * 512 + t;
      int row = idx >> 4, col = (idx & 15) * 8;
      if (bm + row < Mvalid)
        *(uint4*)(&C[(size_t)(bm + row) * Nn + bn + col]) = *(const uint4*)(&sh[row * 128 + col]);
    }
  } else {
    float* Cf = (float*)Cv;
    float* shf = (float*)sh;  // 128 x 128 f32 = 64KB, single pass
    #pragma unroll
    for (int j = 0; j < 2; j++) {
      int col = wn + j * 16 + m16;
      float bv = bias ? bias[bn + col] : 0.f;
      #pragma unroll
      for (int i = 0; i < 4; i++)
        #pragma unroll
        for (int r = 0; r < 4; r++)
          shf[(wm + i * 16 + quad * 4 + r) * 128 + col] = acc[i][j][r] + bv;
    }
    __syncthreads();
    #pragma unroll
    for (int c = 0; c < 8; c++) {
      int idx = c * 512 + t;
      int row = idx >> 5, col = (idx & 31) * 4;
      if (bm + row < Mvalid)
        *(float4*)(&Cf[(size_t)(bm + row) * Nn + bn + col]) =
            *(const float4*)(&shf[row * 128 + col]);
    }
  }
}

// ---------------- block-wide sum helper (512 threads) ----------------
__device__ __forceinline__ float block_sum512(float v, float* red) {
  int t = threadIdx.x;
  red[t] = v;
  __syncthreads();
  for (int st = 256; st > 0; st >>= 1) {
    if (t < st) red[t] += red[t + st];
    __syncthreads();
  }
  float r = red[0];
  __syncthreads();
  return r;
}

// ---------------- fused attention, r13: 512 threads / 8 waves ----------------
// blocks 0..767 = main rows (MFMA), blocks 768..863 = CLS row. Same 128-row
// tile, same 37888B LDS pool, same 3-barrier/jt cadence (r10: fewer barriers
// regresses). r13 applies the r12 occupancy lever: 8 waves/block, each wave
// owns 16 q-rows (nt-loop gone: qb[2], sacc[4], oacc[4], ~half the VGPR);
// K/V staging spread over 512 threads (1xuint4 K, 2xuint2 V per thread).
// Residency: 4 blocks/CU possible, grid 864 -> ~3.4 blocks = ~27 waves/CU
// (was ~13.5) to hide the barrier stalls. P-pack = pkbf2 (cvtpk-after-__expf
// is a verified miscompile, r4/r7/r8).
__global__ __launch_bounds__(512) void attn_fused(
    const unsigned short* __restrict__ qkv, const float* __restrict__ canny,
    const float* __restrict__ noise, unsigned short* __restrict__ attn_out) {
  __shared__ __align__(16) char pool[37888];
  int id = blockIdx.x;
  int t = threadIdx.x;

  if (id < 768) {
    // ================= main path =================
    short* ps = (short*)pool;                          // 128*72 shorts
    short* ks = (short*)(pool + 18432);                // 64*72 shorts
    unsigned int* vs = (unsigned int*)(pool + 27648);  // 64*36 words
    float* tailbuf = (float*)(pool + 36864);           // 256 floats

    int tile = id / 96;
    int rem = id % 96;
    int h = rem >> 3;
    int b = rem & 7;
    int lane = t & 63, w = t >> 6;          // w in 0..7, wave owns rows w*16..+15
    int m16 = lane & 15, quad = lane >> 4;

    int qbase = 1 + tile * 128;

    // ---- stage Q (each wave stages exactly its own 16 rows; 32B/thread)
    {
      int r = t >> 2, seg = (t & 3) * 16;
      const uint4* src = (const uint4*)(qkv + (size_t)(b * N_ + qbase + r) * QKVC_ + h * 64 + seg);
      uint4 u0 = src[0], u1 = src[1];
      *(uint4*)(&ps[r * 72 + seg])     = u0;
      *(uint4*)(&ps[r * 72 + seg + 8]) = u1;
    }
    // ---- Q B-operand fragments, pre-scaled by SCALE_ (so P = __expf(s) later)
    s16x8 qb[2];
    #pragma unroll
    for (int ks_ = 0; ks_ < 2; ks_++) {
      qb[ks_] = *(const s16x8*)(&ps[(w * 16 + m16) * 72 + ks_ * 32 + quad * 8]);
      unsigned int* u = (unsigned int*)&qb[ks_];
      #pragma unroll
      for (int i = 0; i < 4; i++)
        u[i] = pkbf2(blo(u[i]) * SCALE_, bhi(u[i]) * SCALE_);
    }
    // ones fragment for row-sum MFMA
    s16x8 vone;
    #pragma unroll
    for (int i = 0; i < 8; i++) vone[i] = (short)0x3F80;

    f32x4 oacc[4], lacc;
    lacc = (f32x4){0.f, 0.f, 0.f, 0.f};
    #pragma unroll
    for (int dt = 0; dt < 4; dt++) oacc[dt] = (f32x4){0.f, 0.f, 0.f, 0.f};

    // ---- prefetch addressing (512 threads: 1 uint4 K + 2 uint2 V each)
    int kkey = t >> 3, kseg = (t & 7) * 8;
    const unsigned short* kbase = qkv + (size_t)(b * N_) * QKVC_ + D_ + h * 64;
    int vp2 = t & 31, vseg = t >> 5;  // vseg 0..15, dims vseg*4..+3
    const unsigned short* vbase = qkv + (size_t)(b * N_) * QKVC_ + 2 * D_ + h * 64 + vseg * 4;
    uint4 kr0; uint2 vr0, vr1;
    {
      kr0 = *(const uint4*)(kbase + (size_t)kkey * QKVC_ + kseg);
      vr0 = *(const uint2*)(vbase + (size_t)(2 * vp2) * QKVC_);
      vr1 = *(const uint2*)(vbase + (size_t)(2 * vp2 + 1) * QKVC_);
    }

    for (int jt = 0; jt < 16; jt++) {
      __syncthreads();  // prior QK(ks)/PV(vs) reads complete
      // ---- write prefetched K tile [key][hd]
      *(uint4*)(&ks[kkey * 72 + kseg]) = kr0;
      // ---- write prefetched V^T tile [dim][keypair] (perm pack, 4 dims/thread)
      {
        const unsigned int* vaw = (const unsigned int*)&vr0;
        const unsigned int* vbw = (const unsigned int*)&vr1;
        #pragma unroll
        for (int i = 0; i < 2; i++) {
          vs[(vseg * 4 + 2 * i)     * 36 + vp2] = __builtin_amdgcn_perm(vbw[i], vaw[i], 0x05040100u);
          vs[(vseg * 4 + 2 * i + 1) * 36 + vp2] = __builtin_amdgcn_perm(vbw[i], vaw[i], 0x07060302u);
        }
      }
      __syncthreads();  // staging visible (no global loads in flight here)
      // ---- issue next tile's loads; they overlap QK+exp, drain at next barrier
      if (jt < 15) {
        int j0 = (jt + 1) * 64;
        kr0 = *(const uint4*)(kbase + (size_t)(j0 + kkey) * QKVC_ + kseg);
        vr0 = *(const uint2*)(vbase + (size_t)(j0 + 2 * vp2) * QKVC_);
        vr1 = *(const uint2*)(vbase + (size_t)(j0 + 2 * vp2 + 1) * QKVC_);
      }
      // ---- QK: S^T[key][qrow] per wave: 4 key-tiles x 1 row-tile (16 rows)
      f32x4 sacc[4];
      #pragma unroll
      for (int kt = 0; kt < 4; kt++) {
        s16x8 ka0 = *(const s16x8*)(&ks[(kt * 16 + m16) * 72 + quad * 8]);
        s16x8 ka1 = *(const s16x8*)(&ks[(kt * 16 + m16) * 72 + 32 + quad * 8]);
        f32x4 s = (f32x4){0.f, 0.f, 0.f, 0.f};
        s = __builtin_amdgcn_mfma_f32_16x16x32_bf16(ka0, qb[0], s, 0, 0, 0);
        s = __builtin_amdgcn_mfma_f32_16x16x32_bf16(ka1, qb[1], s, 0, 0, 0);
        sacc[kt] = s;
      }
      // ---- P = exp(s) (scale pre-folded); perm-pack 4 keys -> b64 write
      #pragma unroll
      for (int kt = 0; kt < 4; kt++) {
        f32x4 s = sacc[kt];
        float p0 = __expf(s[0]);
        float p1 = __expf(s[1]);
        float p2 = __expf(s[2]);
        float p3 = __expf(s[3]);
        uint2 pk = {pkbf2(p0, p1), pkbf2(p2, p3)};
        *(uint2*)(&ps[(w * 16 + m16) * 72 + kt * 16 + quad * 4]) = pk;
      }
      __syncthreads();  // ps visible; prefetch loads drained here (overlapped)
      // ---- PV: O += P·V ; l += P·1 (C-layout row-sums)
      s16x8 pa[2];
      #pragma unroll
      for (int ks_ = 0; ks_ < 2; ks_++)
        pa[ks_] = *(const s16x8*)(&ps[(w * 16 + m16) * 72 + ks_ * 32 + quad * 8]);
      const short* vss = (const short*)vs;
      #pragma unroll
      for (int dt = 0; dt < 4; dt++) {
        s16x8 vb0 = *(const s16x8*)(&vss[(dt * 16 + m16) * 72 + quad * 8]);
        s16x8 vb1 = *(const s16x8*)(&vss[(dt * 16 + m16) * 72 + 32 + quad * 8]);
        oacc[dt] = __builtin_amdgcn_mfma_f32_16x16x32_bf16(pa[0], vb0, oacc[dt], 0, 0, 0);
        oacc[dt] = __builtin_amdgcn_mfma_f32_16x16x32_bf16(pa[1], vb1, oacc[dt], 0, 0, 0);
      }
      lacc = __builtin_amdgcn_mfma_f32_16x16x32_bf16(pa[0], vone, lacc, 0, 0, 0);
      lacc = __builtin_amdgcn_mfma_f32_16x16x32_bf16(pa[1], vone, lacc, 0, 0, 0);
    }
    // ---- tail: key 1024 (q fragments pre-scaled -> p = expf(d))
    if (t < 64)       tailbuf[t]             = bf2f(qkv[(size_t)(b * N_ + 1024) * QKVC_ + D_     + h * 64 + t]);
    else if (t < 128) tailbuf[64 + (t - 64)] = bf2f(qkv[(size_t)(b * N_ + 1024) * QKVC_ + 2 * D_ + h * 64 + (t - 64)]);
    __syncthreads();
    {
      float d = 0.f;
      #pragma unroll
      for (int jj = 0; jj < 8; jj++) {
        d += bf2f((unsigned short)qb[0][jj]) * tailbuf[quad * 8 + jj];
        d += bf2f((unsigned short)qb[1][jj]) * tailbuf[32 + quad * 8 + jj];
      }
      d += __shfl_xor(d, 16, 64);
      d += __shfl_xor(d, 32, 64);
      float p = __expf(d);
      if (quad == 0) tailbuf[128 + w * 16 + m16] = p;
    }
    __syncthreads();
    #pragma unroll
    for (int r = 0; r < 4; r++) {
      float pr = tailbuf[128 + w * 16 + quad * 4 + r];
      lacc[r] += pr;
      #pragma unroll
      for (int dt = 0; dt < 4; dt++)
        oacc[dt][r] += pr * tailbuf[64 + dt * 16 + m16];
    }
    // ---- normalize + store (O layout: row=w*16+quad*4+r, dim=dt*16+m16)
    {
      float rinv[4];
      #pragma unroll
      for (int r = 0; r < 4; r++) rinv[r] = 1.0f / lacc[r];
      #pragma unroll
      for (int dt = 0; dt < 4; dt++) {
        #pragma unroll
        for (int r = 0; r < 4; r++) {
          int grow = b * N_ + qbase + w * 16 + quad * 4 + r;
          attn_out[(size_t)grow * D_ + h * 64 + dt * 16 + m16] = f2bf(oacc[dt][r] * rinv[r]);
        }
      }
    }
  } else {
    // ================= CLS path (row 0 of each (b,h)), 512 threads =========
    float* s     = (float*)pool;            // 1025 floats            [0,4100)
    float* red   = (float*)(pool + 4608);   // 512 floats             [4608,6656)
    float* q     = (float*)(pool + 6656);   // 64 floats              [6656,6912)
    float* pvred = (float*)(pool + 6912);   // 64*65 floats (+1 pad)  [6912,23552)

    int bh = id - 768;
    int b = bh / H_, h = bh % H_;

    if (t < 64) q[t] = bf2f(qkv[(size_t)(b * N_) * QKVC_ + h * 64 + t]);
    __syncthreads();

    // QK: vectorized uint4 loads (8 x 16B per key row)
    for (int j = t; j < N_; j += 512) {
      const unsigned short* krow = qkv + (size_t)(b * N_ + j) * QKVC_ + D_ + h * 64;
      float dot = 0.f;
      #pragma unroll
      for (int c = 0; c < 8; c++) {
        uint4 kk = *(const uint4*)(krow + c * 8);
        dot += q[c*8+0]*blo(kk.x) + q[c*8+1]*bhi(kk.x)
             + q[c*8+2]*blo(kk.y) + q[c*8+3]*bhi(kk.y)
             + q[c*8+4]*blo(kk.z) + q[c*8+5]*bhi(kk.z)
             + q[c*8+6]*blo(kk.w) + q[c*8+7]*bhi(kk.w);
      }
      s[j] = dot * SCALE_;
    }
    float cp = 0.f, npp = 0.f;
    for (int j = t; j < NP_; j += 512) {
      cp  += canny[b * NP_ + j] + 1.0f;
      npp += noise[b * NP_ + j];
    }
    float csum = block_sum512(cp, red);
    float nsum = block_sum512(npp, red);
    float e1 = 0.f;
    for (int j = t; j < N_; j += 512) if (j >= 1) e1 += __expf(s[j]);
    float sum1 = block_sum512(e1, red);
    for (int j = t; j < N_; j += 512) {
      if (j >= 1) {
        s[j] = __expf(s[j]) / sum1
             + (canny[b * NP_ + j - 1] + 1.0f) / csum
             + noise[b * NP_ + j - 1] / nsum;
      }
    }
    __syncthreads();
    float e2 = 0.f;
    for (int j = t; j < N_; j += 512) { float e = __expf(s[j]); s[j] = e; e2 += e; }
    float sum2 = block_sum512(e2, red);
    // PV: thread owns dim-octet o (8 dims), strides 64 rows -> 1 uint4 load/iter
    {
      int o = t & 7, g = t >> 3;  // g in 0..63
      float a[8] = {0.f, 0.f, 0.f, 0.f, 0.f, 0.f, 0.f, 0.f};
      for (int j = g; j < N_; j += 64) {
        float sv = s[j];
        uint4 vv = *(const uint4*)(qkv + (size_t)(b * N_ + j) * QKVC_ + 2 * D_ + h * 64 + o * 8);
        a[0] += sv * blo(vv.x); a[1] += sv * bhi(vv.x);
        a[2] += sv * blo(vv.y); a[3] += sv * bhi(vv.y);
        a[4] += sv * blo(vv.z); a[5] += sv * bhi(vv.z);
        a[6] += sv * blo(vv.w); a[7] += sv * bhi(vv.w);
      }
      #pragma unroll
      for (int i = 0; i < 8; i++) pvred[(o * 8 + i) * 65 + g] = a[i];
    }
    __syncthreads();
    if (t < 64) {
      float acc = 0.f;
      #pragma unroll
      for (int u = 0; u < 64; u++) acc += pvred[t * 65 + u];
      attn_out[(size_t)(b * N_) * D_ + h * 64 + t] = f2bf(acc / sum2);
    }
  }
}

// ---------------- launch ----------------
extern "C" void kernel_launch(void* const* d_in, const int* in_sizes, int n_in,
                              void* d_out, int out_size, void* d_ws, size_t ws_size,
                              hipStream_t stream) {
  (void)in_sizes; (void)n_in; (void)out_size; (void)ws_size;
  const float* x     = (const float*)d_in[0];
  const float* canny = (const float*)d_in[1];
  const float* noise = (const float*)d_in[2];
  const float* lnw   = (const float*)d_in[3];
  const float* lnb   = (const float*)d_in[4];
  const float* wqkv  = (const float*)d_in[5];
  const float* wout  = (const float*)d_in[6];
  const float* bout  = (const float*)d_in[7];
  float* out = (float*)d_out;
  char* ws = (char*)d_ws;

  unsigned short* xn    = (unsigned short*)(ws);              // 8320*768 bf16 (reused as attn_out)
  unsigned short* wqkvT = (unsigned short*)(ws + 12779520);   // 2304*768
  unsigned short* woutT = (unsigned short*)(ws + 16318464);   // 768*768
  unsigned short* qkv   = (unsigned short*)(ws + 17498112);   // 8200*2304

  prep_fused<<<dim3(2304 + ROWS_), 256, 0, stream>>>(
      wqkv, wqkvT, wout, woutT, x, lnw, lnb, xn);
  gemm_bt<false><<<dim3((QKVC_ / 128) * (ROWS_PAD_ / 128)), 512, 0, stream>>>(
      xn, wqkvT, (void*)qkv, nullptr, ROWS_, QKVC_, D_);
  attn_fused<<<dim3(768 + B_ * H_), 512, 0, stream>>>(qkv, canny, noise, xn);
  gemm_bt<true><<<dim3((D_ / 128) * (ROWS_PAD_ / 128)), 512, 0, stream>>>(
      xn, woutT, (void*)out, bout, ROWS_, D_, D_);
}

// Round 14
// 194.941 us; speedup vs baseline: 1.0814x; 1.0814x over previous
//
#include <hip/hip_runtime.h>

#define B_ 8
#define N_ 1025
#define D_ 768
#define H_ 12
#define NP_ 1024
#define ROWS_ (B_*N_)        /* 8200 */
#define ROWS_PAD_ 8320       /* 65*128 */
#define QKVC_ 2304
#define SCALE_ 0.03608439182435161f  /* 768^-0.5 */
#define EPS_ 1e-5f

typedef float f32x4 __attribute__((ext_vector_type(4)));
typedef short s16x8 __attribute__((ext_vector_type(8)));

// async global->LDS, 16B per lane; lds dest must be wave-uniform base + lane*16
#define GLD16(g, l) __builtin_amdgcn_global_load_lds( \
    (const __attribute__((address_space(1))) unsigned int*)(g), \
    (__attribute__((address_space(3))) unsigned int*)(l), 16, 0, 0)

__device__ __forceinline__ float blo(unsigned int u){
  union { unsigned int i; float f; } v; v.i = u << 16; return v.f;
}
__device__ __forceinline__ float bhi(unsigned int u){
  union { unsigned int i; float f; } v; v.i = u & 0xffff0000u; return v.f;
}
__device__ __forceinline__ float bf2f(unsigned short u){
  union { unsigned int i; float f; } v; v.i = ((unsigned int)u) << 16; return v.f;
}
__device__ __forceinline__ unsigned short f2bf(float f){
  union { unsigned int i; float f; } v; v.f = f;
  unsigned int b = v.i;
  b = b + 0x7fffu + ((b >> 16) & 1u);
  return (unsigned short)(b >> 16);
}
// pack two f32 -> two bf16 (round-half-up, bit-identical to f2bf pairs), 3 VALU.
// NOTE (r4/r7/r8, isolated by r8-vs-r9): do NOT replace with inline-asm
// v_cvt_pk_bf16_f32 when inputs come from __expf/v_exp_f32 -- the TRANS-op
// latency hazard is not fenced ahead of INLINEASM consumers (reads stale regs,
// absmax ~1.4e-2). pkbf2 uses compiler-visible ops -> hazard handled.
// NOTE (r10): removing the post-exp attn barrier REGRESSES (+5.5us).
// NOTE (r11): GEMM BK=32 retile regresses (+10us): step count is the cost.
// NOTE (r12): 512-thr/8-wave GEMM at SAME geometry = -7us (occupancy lever).
// NOTE (r13): 512-thr attn REGRESSES (+2.3us): uint2 V-prefetch breaks
// coalescing (FETCH +30%), conflicts +57%. Keep 256-thr attn.
__device__ __forceinline__ unsigned int pkbf2(float a, float b){
  union { float f; unsigned int i; } ua, ub;
  ua.f = a; ub.f = b;
  return __builtin_amdgcn_perm(ub.i + 0x8000u, ua.i + 0x8000u, 0x07060302u);
}

// ---------------- prep: fused weight transposes + layernorm ----------------
__global__ __launch_bounds__(256) void prep_fused(
    const float* __restrict__ w1, unsigned short* __restrict__ d1,
    const float* __restrict__ w2, unsigned short* __restrict__ d2,
    const float* __restrict__ x, const float* __restrict__ lw,
    const float* __restrict__ lb, unsigned short* __restrict__ xn) {
  int id = blockIdx.x;
  int t = threadIdx.x;
  if (id < 2304) {
    __shared__ unsigned short tile[32][33];
    int bx = id % 96;
    int kb = (id / 96) * 32;
    const float* src; unsigned short* dst; int N, nb;
    if (bx < 72) { src = w1; dst = d1; N = QKVC_; nb = bx * 32; }
    else         { src = w2; dst = d2; N = D_;    nb = (bx - 72) * 32; }
    int tx = t & 31, ty = t >> 5;  // 32 x 8
    #pragma unroll
    for (int i = 0; i < 4; i++) {
      int r = ty + i * 8;
      tile[r][tx] = f2bf(src[(size_t)(kb + r) * N + nb + tx]);
    }
    __syncthreads();
    #pragma unroll
    for (int i = 0; i < 4; i++) {
      int r = ty + i * 8;
      dst[(size_t)(nb + r) * D_ + kb + tx] = tile[tx][r];
    }
  } else {
    int row = id - 2304;
    __shared__ float r6[6];
    float4 v; float s = 0.f, q = 0.f;
    if (t < 192) {
      v = ((const float4*)(x + (size_t)row * D_))[t];
      s = v.x + v.y + v.z + v.w;
      q = v.x * v.x + v.y * v.y + v.z * v.z + v.w * v.w;
      #pragma unroll
      for (int off = 32; off > 0; off >>= 1) {
        s += __shfl_xor(s, off, 64);
        q += __shfl_xor(q, off, 64);
      }
      if ((t & 63) == 0) { r6[t >> 6] = s; r6[3 + (t >> 6)] = q; }
    }
    __syncthreads();
    if (t < 192) {
      s = r6[0] + r6[1] + r6[2];
      q = r6[3] + r6[4] + r6[5];
      float mean = s * (1.0f / 768.0f);
      float var = q * (1.0f / 768.0f) - mean * mean;
      var = var < 0.f ? 0.f : var;
      float rstd = rsqrtf(var + EPS_);
      float4 wv4 = ((const float4*)lw)[t];
      float4 bv4 = ((const float4*)lb)[t];
      float o0 = (v.x - mean) * rstd * wv4.x + bv4.x;
      float o1 = (v.y - mean) * rstd * wv4.y + bv4.y;
      float o2 = (v.z - mean) * rstd * wv4.z + bv4.z;
      float o3 = (v.w - mean) * rstd * wv4.w + bv4.w;
      uint2 pk = {pkbf2(o0, o1), pkbf2(o2, o3)};
      *(uint2*)(xn + (size_t)row * D_ + t * 4) = pk;
    }
  }
}

// ---------------- GEMM (r12, best measured) ----------------
template <bool OF32>
__global__ __launch_bounds__(512) void gemm_bt(
    const unsigned short* __restrict__ A, const unsigned short* __restrict__ Bt,
    void* __restrict__ Cv, const float* __restrict__ bias,
    int Mvalid, int Nn, int Kk) {
  __shared__ short sh[32768];
  int t = threadIdx.x;
  int lane = t & 63, w = t >> 6;
  int m16 = lane & 15, quad = lane >> 4;

  int nwg = gridDim.x;
  int nbx = Nn >> 7;
  int id = blockIdx.x;
  int qq = nwg >> 3, rr = nwg & 7;
  int xcd = id & 7, off = id >> 3;
  int wg = (xcd < rr ? xcd * (qq + 1) : rr * (qq + 1) + (xcd - rr) * qq) + off;
  int bx = wg % nbx, by = wg / nbx;
  int bm = by * 128, bn = bx * 128;

  int wm = (w & 1) * 64, wn = (w >> 1) * 32;

  f32x4 acc[4][2];
  #pragma unroll
  for (int i = 0; i < 4; i++)
    #pragma unroll
    for (int j = 0; j < 2; j++) acc[i][j] = (f32x4){0.f, 0.f, 0.f, 0.f};

  const unsigned short* aP[2];
  const unsigned short* bP[2];
  #pragma unroll
  for (int c = 0; c < 2; c++) {
    int g = t + c * 512;
    int row = g >> 3, slot = g & 7;
    aP[c] = A  + (size_t)(bm + row) * Kk + ((slot ^ (row & 7)) * 8);
    bP[c] = Bt + (size_t)(bn + row) * Kk + ((slot ^ (row & 7)) * 8);
  }

  int KS = Kk >> 6;
  int cur = 0;
  #pragma unroll
  for (int c = 0; c < 2; c++) GLD16(aP[c], sh + (t + c * 512) * 8);
  #pragma unroll
  for (int c = 0; c < 2; c++) GLD16(bP[c], sh + 16384 + (t + c * 512) * 8);

  for (int kt = 0; kt < KS; kt++) {
    asm volatile("s_waitcnt vmcnt(0)" ::: "memory");
    __builtin_amdgcn_s_barrier();
    if (kt + 1 < KS) {
      int nb2 = (cur ^ 1) * 8192;
      int ko = (kt + 1) * 64;
      #pragma unroll
      for (int c = 0; c < 2; c++) GLD16(aP[c] + ko, sh + nb2 + (t + c * 512) * 8);
      #pragma unroll
      for (int c = 0; c < 2; c++) GLD16(bP[c] + ko, sh + 16384 + nb2 + (t + c * 512) * 8);
    }
    const short* sa = sh + cur * 8192;
    const short* sb = sh + 16384 + cur * 8192;
    #pragma unroll
    for (int ks = 0; ks < 2; ks++) {
      int so = ((ks * 4 + quad) ^ (m16 & 7)) * 8;
      s16x8 af[4], bfr[2];
      #pragma unroll
      for (int i = 0; i < 4; i++)
        af[i] = *(const s16x8*)(sa + (wm + i * 16 + m16) * 64 + so);
      #pragma unroll
      for (int j = 0; j < 2; j++)
        bfr[j] = *(const s16x8*)(sb + (wn + j * 16 + m16) * 64 + so);
      __builtin_amdgcn_s_setprio(1);
      #pragma unroll
      for (int i = 0; i < 4; i++)
        #pragma unroll
        for (int j = 0; j < 2; j++)
          acc[i][j] = __builtin_amdgcn_mfma_f32_16x16x32_bf16(af[i], bfr[j], acc[i][j], 0, 0, 0);
      __builtin_amdgcn_s_setprio(0);
    }
    cur ^= 1;
  }
  __syncthreads();

  if (!OF32) {
    unsigned short* C = (unsigned short*)Cv;
    #pragma unroll
    for (int j = 0; j < 2; j++) {
      int col = wn + j * 16 + m16;
      #pragma unroll
      for (int i = 0; i < 4; i++)
        #pragma unroll
        for (int r = 0; r < 4; r++)
          sh[(wm + i * 16 + quad * 4 + r) * 128 + col] = (short)f2bf(acc[i][j][r]);
    }
    __syncthreads();
    #pragma unroll
    for (int c = 0; c < 4; c++) {
      int idx = c * 512 + t;
      int row = idx >> 4, col = (idx & 15) * 8;
      if (bm + row < Mvalid)
        *(uint4*)(&C[(size_t)(bm + row) * Nn + bn + col]) = *(const uint4*)(&sh[row * 128 + col]);
    }
  } else {
    float* Cf = (float*)Cv;
    float* shf = (float*)sh;
    #pragma unroll
    for (int j = 0; j < 2; j++) {
      int col = wn + j * 16 + m16;
      float bv = bias ? bias[bn + col] : 0.f;
      #pragma unroll
      for (int i = 0; i < 4; i++)
        #pragma unroll
        for (int r = 0; r < 4; r++)
          shf[(wm + i * 16 + quad * 4 + r) * 128 + col] = acc[i][j][r] + bv;
    }
    __syncthreads();
    #pragma unroll
    for (int c = 0; c < 8; c++) {
      int idx = c * 512 + t;
      int row = idx >> 5, col = (idx & 31) * 4;
      if (bm + row < Mvalid)
        *(float4*)(&Cf[(size_t)(bm + row) * Nn + bn + col]) =
            *(const float4*)(&shf[row * 128 + col]);
    }
  }
}

// ---------------- block-wide sum helper (256 threads) ----------------
__device__ __forceinline__ float block_sum(float v, float* red) {
  int t = threadIdx.x;
  red[t] = v;
  __syncthreads();
  for (int st = 128; st > 0; st >>= 1) {
    if (t < st) red[t] += red[t + st];
    __syncthreads();
  }
  float r = red[0];
  __syncthreads();
  return r;
}

// ---------------- fused attention (r9/r12 structure, 256 threads) ----------
__global__ __launch_bounds__(256) void attn_fused(
    const unsigned short* __restrict__ qkv, const float* __restrict__ canny,
    const float* __restrict__ noise, unsigned short* __restrict__ attn_out) {
  __shared__ __align__(16) char pool[37888];
  int id = blockIdx.x;
  int t = threadIdx.x;

  if (id < 768) {
    short* ps = (short*)pool;                          // 128*72 shorts
    short* ks = (short*)(pool + 18432);                // 64*72 shorts
    unsigned int* vs = (unsigned int*)(pool + 27648);  // 64*36 words
    float* tailbuf = (float*)(pool + 36864);           // 256 floats

    int tile = id / 96;
    int rem = id % 96;
    int h = rem >> 3;
    int b = rem & 7;
    int lane = t & 63, w = t >> 6;
    int m16 = lane & 15, quad = lane >> 4;

    int qbase = 1 + tile * 128;

    {
      int r = t >> 1, seg = (t & 1) * 32;
      const uint4* src = (const uint4*)(qkv + (size_t)(b * N_ + qbase + r) * QKVC_ + h * 64 + seg);
      uint4 u0 = src[0], u1 = src[1], u2 = src[2], u3 = src[3];
      *(uint4*)(&ps[r * 72 + seg])      = u0;
      *(uint4*)(&ps[r * 72 + seg + 8])  = u1;
      *(uint4*)(&ps[r * 72 + seg + 16]) = u2;
      *(uint4*)(&ps[r * 72 + seg + 24]) = u3;
    }
    s16x8 qb[2][2];
    #pragma unroll
    for (int nt = 0; nt < 2; nt++)
      #pragma unroll
      for (int ks_ = 0; ks_ < 2; ks_++) {
        qb[nt][ks_] = *(const s16x8*)(&ps[(w * 32 + nt * 16 + m16) * 72 + ks_ * 32 + quad * 8]);
        unsigned int* u = (unsigned int*)&qb[nt][ks_];
        #pragma unroll
        for (int i = 0; i < 4; i++)
          u[i] = pkbf2(blo(u[i]) * SCALE_, bhi(u[i]) * SCALE_);
      }
    s16x8 vone;
    #pragma unroll
    for (int i = 0; i < 8; i++) vone[i] = (short)0x3F80;

    f32x4 oacc[2][4], lacc[2];
    #pragma unroll
    for (int mt = 0; mt < 2; mt++) {
      lacc[mt] = (f32x4){0.f, 0.f, 0.f, 0.f};
      #pragma unroll
      for (int dt = 0; dt < 4; dt++) oacc[mt][dt] = (f32x4){0.f, 0.f, 0.f, 0.f};
    }

    int kkey = t >> 2, kseg = (t & 3) * 16;
    const unsigned short* kbase = qkv + (size_t)(b * N_) * QKVC_ + D_ + h * 64;
    int vp2 = t & 31, vseg = t >> 5;
    const unsigned short* vbase = qkv + (size_t)(b * N_) * QKVC_ + 2 * D_ + h * 64 + vseg * 8;
    uint4 kr0, kr1, vr0, vr1;
    {
      const uint4* ksrc = (const uint4*)(kbase + (size_t)kkey * QKVC_ + kseg);
      kr0 = ksrc[0]; kr1 = ksrc[1];
      vr0 = *(const uint4*)(vbase + (size_t)(2 * vp2) * QKVC_);
      vr1 = *(const uint4*)(vbase + (size_t)(2 * vp2 + 1) * QKVC_);
    }

    for (int jt = 0; jt < 16; jt++) {
      __syncthreads();
      *(uint4*)(&ks[kkey * 72 + kseg])     = kr0;
      *(uint4*)(&ks[kkey * 72 + kseg + 8]) = kr1;
      {
        const unsigned int* vaw = (const unsigned int*)&vr0;
        const unsigned int* vbw = (const unsigned int*)&vr1;
        #pragma unroll
        for (int i = 0; i < 4; i++) {
          vs[(vseg * 8 + 2 * i)     * 36 + vp2] = __builtin_amdgcn_perm(vbw[i], vaw[i], 0x05040100u);
          vs[(vseg * 8 + 2 * i + 1) * 36 + vp2] = __builtin_amdgcn_perm(vbw[i], vaw[i], 0x07060302u);
        }
      }
      __syncthreads();
      if (jt < 15) {
        int j0 = (jt + 1) * 64;
        const uint4* ksrc = (const uint4*)(kbase + (size_t)(j0 + kkey) * QKVC_ + kseg);
        kr0 = ksrc[0]; kr1 = ksrc[1];
        vr0 = *(const uint4*)(vbase + (size_t)(j0 + 2 * vp2) * QKVC_);
        vr1 = *(const uint4*)(vbase + (size_t)(j0 + 2 * vp2 + 1) * QKVC_);
      }
      f32x4 sacc[4][2];
      #pragma unroll
      for (int kt = 0; kt < 4; kt++) {
        s16x8 ka0 = *(const s16x8*)(&ks[(kt * 16 + m16) * 72 + quad * 8]);
        s16x8 ka1 = *(const s16x8*)(&ks[(kt * 16 + m16) * 72 + 32 + quad * 8]);
        #pragma unroll
        for (int nt = 0; nt < 2; nt++) {
          f32x4 s = (f32x4){0.f, 0.f, 0.f, 0.f};
          s = __builtin_amdgcn_mfma_f32_16x16x32_bf16(ka0, qb[nt][0], s, 0, 0, 0);
          s = __builtin_amdgcn_mfma_f32_16x16x32_bf16(ka1, qb[nt][1], s, 0, 0, 0);
          sacc[kt][nt] = s;
        }
      }
      #pragma unroll
      for (int kt = 0; kt < 4; kt++) {
        #pragma unroll
        for (int nt = 0; nt < 2; nt++) {
          f32x4 s = sacc[kt][nt];
          float p0 = __expf(s[0]);
          float p1 = __expf(s[1]);
          float p2 = __expf(s[2]);
          float p3 = __expf(s[3]);
          uint2 pk = {pkbf2(p0, p1), pkbf2(p2, p3)};
          *(uint2*)(&ps[(w * 32 + nt * 16 + m16) * 72 + kt * 16 + quad * 4]) = pk;
        }
      }
      __syncthreads();
      s16x8 pa[2][2];
      #pragma unroll
      for (int mt = 0; mt < 2; mt++)
        #pragma unroll
        for (int ks_ = 0; ks_ < 2; ks_++)
          pa[mt][ks_] = *(const s16x8*)(&ps[(w * 32 + mt * 16 + m16) * 72 + ks_ * 32 + quad * 8]);
      const short* vss = (const short*)vs;
      #pragma unroll
      for (int dt = 0; dt < 4; dt++) {
        s16x8 vb0 = *(const s16x8*)(&vss[(dt * 16 + m16) * 72 + quad * 8]);
        s16x8 vb1 = *(const s16x8*)(&vss[(dt * 16 + m16) * 72 + 32 + quad * 8]);
        #pragma unroll
        for (int mt = 0; mt < 2; mt++) {
          oacc[mt][dt] = __builtin_amdgcn_mfma_f32_16x16x32_bf16(pa[mt][0], vb0, oacc[mt][dt], 0, 0, 0);
          oacc[mt][dt] = __builtin_amdgcn_mfma_f32_16x16x32_bf16(pa[mt][1], vb1, oacc[mt][dt], 0, 0, 0);
        }
      }
      #pragma unroll
      for (int mt = 0; mt < 2; mt++) {
        lacc[mt] = __builtin_amdgcn_mfma_f32_16x16x32_bf16(pa[mt][0], vone, lacc[mt], 0, 0, 0);
        lacc[mt] = __builtin_amdgcn_mfma_f32_16x16x32_bf16(pa[mt][1], vone, lacc[mt], 0, 0, 0);
      }
    }
    if (t < 64)       tailbuf[t]             = bf2f(qkv[(size_t)(b * N_ + 1024) * QKVC_ + D_     + h * 64 + t]);
    else if (t < 128) tailbuf[64 + (t - 64)] = bf2f(qkv[(size_t)(b * N_ + 1024) * QKVC_ + 2 * D_ + h * 64 + (t - 64)]);
    __syncthreads();
    #pragma unroll
    for (int nt = 0; nt < 2; nt++) {
      float d = 0.f;
      #pragma unroll
      for (int jj = 0; jj < 8; jj++) {
        d += bf2f((unsigned short)qb[nt][0][jj]) * tailbuf[quad * 8 + jj];
        d += bf2f((unsigned short)qb[nt][1][jj]) * tailbuf[32 + quad * 8 + jj];
      }
      d += __shfl_xor(d, 16, 64);
      d += __shfl_xor(d, 32, 64);
      float p = __expf(d);
      if (quad == 0) tailbuf[128 + w * 32 + nt * 16 + m16] = p;
    }
    __syncthreads();
    #pragma unroll
    for (int mt = 0; mt < 2; mt++)
      #pragma unroll
      for (int r = 0; r < 4; r++) {
        float pr = tailbuf[128 + w * 32 + mt * 16 + quad * 4 + r];
        lacc[mt][r] += pr;
        #pragma unroll
        for (int dt = 0; dt < 4; dt++)
          oacc[mt][dt][r] += pr * tailbuf[64 + dt * 16 + m16];
      }
    #pragma unroll
    for (int mt = 0; mt < 2; mt++) {
      float rinv[4];
      #pragma unroll
      for (int r = 0; r < 4; r++) rinv[r] = 1.0f / lacc[mt][r];
      #pragma unroll
      for (int dt = 0; dt < 4; dt++) {
        #pragma unroll
        for (int r = 0; r < 4; r++) {
          int grow = b * N_ + qbase + w * 32 + mt * 16 + quad * 4 + r;
          attn_out[(size_t)grow * D_ + h * 64 + dt * 16 + m16] = f2bf(oacc[mt][dt][r] * rinv[r]);
        }
      }
    }
  } else {
    float* s     = (float*)pool;            // 1025 floats
    float* red   = (float*)(pool + 4608);   // 256
    float* q     = (float*)(pool + 5632);   // 64
    float* pvred = (float*)(pool + 5888);   // 64*33 floats (+1 pad)

    int bh = id - 768;
    int b = bh / H_, h = bh % H_;

    if (t < 64) q[t] = bf2f(qkv[(size_t)(b * N_) * QKVC_ + h * 64 + t]);
    __syncthreads();

    for (int j = t; j < N_; j += 256) {
      const unsigned short* krow = qkv + (size_t)(b * N_ + j) * QKVC_ + D_ + h * 64;
      float dot = 0.f;
      #pragma unroll
      for (int c = 0; c < 8; c++) {
        uint4 kk = *(const uint4*)(krow + c * 8);
        dot += q[c*8+0]*blo(kk.x) + q[c*8+1]*bhi(kk.x)
             + q[c*8+2]*blo(kk.y) + q[c*8+3]*bhi(kk.y)
             + q[c*8+4]*blo(kk.z) + q[c*8+5]*bhi(kk.z)
             + q[c*8+6]*blo(kk.w) + q[c*8+7]*bhi(kk.w);
      }
      s[j] = dot * SCALE_;
    }
    float cp = 0.f, npp = 0.f;
    for (int j = t; j < NP_; j += 256) {
      cp  += canny[b * NP_ + j] + 1.0f;
      npp += noise[b * NP_ + j];
    }
    float csum = block_sum(cp, red);
    float nsum = block_sum(npp, red);
    float e1 = 0.f;
    for (int j = t; j < N_; j += 256) if (j >= 1) e1 += __expf(s[j]);
    float sum1 = block_sum(e1, red);
    for (int j = t; j < N_; j += 256) {
      if (j >= 1) {
        s[j] = __expf(s[j]) / sum1
             + (canny[b * NP_ + j - 1] + 1.0f) / csum
             + noise[b * NP_ + j - 1] / nsum;
      }
    }
    __syncthreads();
    float e2 = 0.f;
    for (int j = t; j < N_; j += 256) { float e = __expf(s[j]); s[j] = e; e2 += e; }
    float sum2 = block_sum(e2, red);
    {
      int o = t & 7, g = t >> 3;
      float a[8] = {0.f, 0.f, 0.f, 0.f, 0.f, 0.f, 0.f, 0.f};
      for (int j = g; j < N_; j += 32) {
        float sv = s[j];
        uint4 vv = *(const uint4*)(qkv + (size_t)(b * N_ + j) * QKVC_ + 2 * D_ + h * 64 + o * 8);
        a[0] += sv * blo(vv.x); a[1] += sv * bhi(vv.x);
        a[2] += sv * blo(vv.y); a[3] += sv * bhi(vv.y);
        a[4] += sv * blo(vv.z); a[5] += sv * bhi(vv.z);
        a[6] += sv * blo(vv.w); a[7] += sv * bhi(vv.w);
      }
      #pragma unroll
      for (int i = 0; i < 8; i++) pvred[(o * 8 + i) * 33 + g] = a[i];
    }
    __syncthreads();
    if (t < 64) {
      float acc = 0.f;
      #pragma unroll
      for (int u = 0; u < 32; u++) acc += pvred[t * 33 + u];
      attn_out[(size_t)(b * N_) * D_ + h * 64 + t] = f2bf(acc / sum2);
    }
  }
}

// ---------------- launch ----------------
extern "C" void kernel_launch(void* const* d_in, const int* in_sizes, int n_in,
                              void* d_out, int out_size, void* d_ws, size_t ws_size,
                              hipStream_t stream) {
  (void)in_sizes; (void)n_in; (void)out_size; (void)ws_size;
  const float* x     = (const float*)d_in[0];
  const float* canny = (const float*)d_in[1];
  const float* noise = (const float*)d_in[2];
  const float* lnw   = (const float*)d_in[3];
  const float* lnb   = (const float*)d_in[4];
  const float* wqkv  = (const float*)d_in[5];
  const float* wout  = (const float*)d_in[6];
  const float* bout  = (const float*)d_in[7];
  float* out = (float*)d_out;
  char* ws = (char*)d_ws;

  unsigned short* xn    = (unsigned short*)(ws);              // 8320*768 bf16 (reused as attn_out)
  unsigned short* wqkvT = (unsigned short*)(ws + 12779520);   // 2304*768
  unsigned short* woutT = (unsigned short*)(ws + 16318464);   // 768*768
  unsigned short* qkv   = (unsigned short*)(ws + 17498112);   // 8200*2304

  prep_fused<<<dim3(2304 + ROWS_), 256, 0, stream>>>(
      wqkv, wqkvT, wout, woutT, x, lnw, lnb, xn);
  gemm_bt<false><<<dim3((QKVC_ / 128) * (ROWS_PAD_ / 128)), 512, 0, stream>>>(
      xn, wqkvT, (void*)qkv, nullptr, ROWS_, QKVC_, D_);
  attn_fused<<<dim3(768 + B_ * H_), 256, 0, stream>>>(qkv, canny, noise, xn);
  gemm_bt<true><<<dim3((D_ / 128) * (ROWS_PAD_ / 128)), 512, 0, stream>>>(
      xn, woutT, (void*)out, bout, ROWS_, D_, D_);
}